// Round 1
// baseline (1885.549 us; speedup 1.0000x reference)
//
#include <hip/hip_runtime.h>
#include <math.h>

#define NNODES 50000
#define NEDGES 800000
#define FIN    1433
#define HDIM   256
#define NCLS   7

// ---------------- CSR construction ----------------

__global__ void count_kernel(const int* __restrict__ col, int* __restrict__ cnt, int E) {
    int e = blockIdx.x * blockDim.x + threadIdx.x;
    if (e < E) atomicAdd(&cnt[col[e]], 1);
}

__global__ void dinv_kernel(const int* __restrict__ cnt, float* __restrict__ dinv, int n) {
    int i = blockIdx.x * blockDim.x + threadIdx.x;
    if (i < n) dinv[i] = rsqrtf((float)(cnt[i] + 1));   // +1 = self loop; deg always >0
}

__global__ __launch_bounds__(1024) void scan_kernel(const int* __restrict__ cnt,
                                                    int* __restrict__ rp, int n, int total) {
    __shared__ int sums[1024];
    int t = threadIdx.x;
    int chunk = (n + 1023) >> 10;
    int start = t * chunk;
    int end = start + chunk; if (end > n) end = n;
    int local = 0;
    for (int j = start; j < end; ++j) local += cnt[j];
    sums[t] = local;
    __syncthreads();
    for (int off = 1; off < 1024; off <<= 1) {
        int v = (t >= off) ? sums[t - off] : 0;
        __syncthreads();
        sums[t] += v;
        __syncthreads();
    }
    int run = (t == 0) ? 0 : sums[t - 1];
    for (int j = start; j < end; ++j) { rp[j] = run; run += cnt[j]; }
    if (t == 0) rp[n] = total;
}

__global__ void fill_kernel(const int* __restrict__ row, const int* __restrict__ col,
                            const int* __restrict__ rp, int* __restrict__ cur,
                            int* __restrict__ csr, int E) {
    int e = blockIdx.x * blockDim.x + threadIdx.x;
    if (e < E) {
        int c = col[e];
        int pos = rp[c] + atomicAdd(&cur[c], 1);
        csr[pos] = row[e];
    }
}

// ---------------- f32 tiled matmul: C[M,Nn] = A[M,K] @ B[K,Nn] ----------------
// BM=BN=64, BK=16, 256 threads, 4x4 per thread.

__global__ __launch_bounds__(256) void mm_kernel(const float* __restrict__ A,
                                                 const float* __restrict__ B,
                                                 float* __restrict__ C,
                                                 int M, int K, int Nn) {
    __shared__ float As[16][68];   // padded: write pattern As[kk][r] -> 2-way max
    __shared__ float Bs[16][64];
    int tid = threadIdx.x;
    int m0 = blockIdx.x * 64;
    int n0 = blockIdx.y * 64;
    int tx = tid & 15, ty = tid >> 4;
    float acc[4][4] = {};

    for (int k0 = 0; k0 < K; k0 += 16) {
        #pragma unroll
        for (int i = 0; i < 4; ++i) {
            int idx = tid + i * 256;
            int r = idx >> 4, kk = idx & 15;
            int gm = m0 + r, gk = k0 + kk;
            As[kk][r] = (gm < M && gk < K) ? A[gm * K + gk] : 0.f;
        }
        #pragma unroll
        for (int i = 0; i < 4; ++i) {
            int idx = tid + i * 256;
            int kk = idx >> 6, n = idx & 63;
            int gk = k0 + kk;
            Bs[kk][n] = (gk < K) ? B[gk * Nn + n0 + n] : 0.f;
        }
        __syncthreads();
        #pragma unroll
        for (int kk = 0; kk < 16; ++kk) {
            float4 av = *(const float4*)&As[kk][ty * 4];
            float4 bv = *(const float4*)&Bs[kk][tx * 4];
            float a4[4] = {av.x, av.y, av.z, av.w};
            float b4[4] = {bv.x, bv.y, bv.z, bv.w};
            #pragma unroll
            for (int i = 0; i < 4; ++i)
                #pragma unroll
                for (int j = 0; j < 4; ++j)
                    acc[i][j] += a4[i] * b4[j];
        }
        __syncthreads();
    }
    #pragma unroll
    for (int i = 0; i < 4; ++i) {
        int gm = m0 + ty * 4 + i;
        if (gm < M) {
            float4 v = make_float4(acc[i][0], acc[i][1], acc[i][2], acc[i][3]);
            *(float4*)&C[gm * Nn + n0 + tx * 4] = v;
        }
    }
}

// ---------------- aggregation (F=256): one wave per node, float4 per lane ----------------

__global__ __launch_bounds__(256) void agg_kernel(const float4* __restrict__ h,
                                                  float4* __restrict__ out,
                                                  const float* __restrict__ dinv,
                                                  const int* __restrict__ rp,
                                                  const int* __restrict__ csr,
                                                  const float* __restrict__ bias,
                                                  int n) {
    int node = blockIdx.x * 4 + (threadIdx.x >> 6);
    int lane = threadIdx.x & 63;
    if (node >= n) return;
    float di = dinv[node];
    float4 acc = h[node * 64 + lane];
    float sw = di * di;              // self-loop norm
    acc.x *= sw; acc.y *= sw; acc.z *= sw; acc.w *= sw;
    int p0 = rp[node], p1 = rp[node + 1];
    for (int p = p0; p < p1; ++p) {
        int s = csr[p];
        float wgt = dinv[s] * di;
        float4 hv = h[s * 64 + lane];
        acc.x += wgt * hv.x; acc.y += wgt * hv.y;
        acc.z += wgt * hv.z; acc.w += wgt * hv.w;
    }
    float4 b = ((const float4*)bias)[lane];
    acc.x = fmaxf(acc.x + b.x, 0.f);
    acc.y = fmaxf(acc.y + b.y, 0.f);
    acc.z = fmaxf(acc.z + b.z, 0.f);
    acc.w = fmaxf(acc.w + b.w, 0.f);
    out[node * 64 + lane] = acc;
}

// ---------------- layer-3 matmul: h3[N,7] = a[N,256] @ W3[256,7] (wave/node) ----------------

__global__ __launch_bounds__(256) void mm3_kernel(const float4* __restrict__ a,
                                                  const float* __restrict__ W3,
                                                  float* __restrict__ h3, int n) {
    __shared__ float Ws[HDIM * NCLS];   // 1792 = 7*256
    int tid = threadIdx.x;
    #pragma unroll
    for (int k = 0; k < 7; ++k) Ws[tid + k * 256] = W3[tid + k * 256];
    __syncthreads();
    int node = blockIdx.x * 4 + (tid >> 6);
    int lane = tid & 63;
    if (node < n) {
        float4 av = a[node * 64 + lane];
        float av4[4] = {av.x, av.y, av.z, av.w};
        const float* w0 = &Ws[(4 * lane) * NCLS];
        float p[NCLS] = {};
        #pragma unroll
        for (int j = 0; j < 4; ++j)
            #pragma unroll
            for (int c = 0; c < NCLS; ++c)
                p[c] += av4[j] * w0[j * NCLS + c];
        #pragma unroll
        for (int c = 0; c < NCLS; ++c) {
            float v = p[c];
            for (int off = 32; off > 0; off >>= 1) v += __shfl_down(v, off);
            if (lane == 0) h3[node * NCLS + c] = v;
        }
    }
}

// ---------------- layer-3 aggregation + bias + log_softmax ----------------

__global__ void final_kernel(const float* __restrict__ h3, const float* __restrict__ dinv,
                             const int* __restrict__ rp, const int* __restrict__ csr,
                             const float* __restrict__ b3, float* __restrict__ out, int n) {
    int i = blockIdx.x * blockDim.x + threadIdx.x;
    if (i >= n) return;
    float di = dinv[i];
    float sw = di * di;
    float acc[NCLS];
    #pragma unroll
    for (int c = 0; c < NCLS; ++c) acc[c] = sw * h3[i * NCLS + c];
    int p0 = rp[i], p1 = rp[i + 1];
    for (int p = p0; p < p1; ++p) {
        int s = csr[p];
        float wgt = dinv[s] * di;
        #pragma unroll
        for (int c = 0; c < NCLS; ++c) acc[c] += wgt * h3[s * NCLS + c];
    }
    float mx = -1e30f;
    #pragma unroll
    for (int c = 0; c < NCLS; ++c) { acc[c] += b3[c]; mx = fmaxf(mx, acc[c]); }
    float sum = 0.f;
    #pragma unroll
    for (int c = 0; c < NCLS; ++c) sum += expf(acc[c] - mx);
    float lse = mx + logf(sum);
    #pragma unroll
    for (int c = 0; c < NCLS; ++c) out[i * NCLS + c] = acc[c] - lse;
}

// ---------------- launch ----------------

extern "C" void kernel_launch(void* const* d_in, const int* in_sizes, int n_in,
                              void* d_out, int out_size, void* d_ws, size_t ws_size,
                              hipStream_t stream) {
    const float* x  = (const float*)d_in[0];
    const int*   ei = (const int*)d_in[1];
    const float* W1 = (const float*)d_in[2];
    const float* b1 = (const float*)d_in[3];
    const float* W2 = (const float*)d_in[4];
    const float* b2 = (const float*)d_in[5];
    const float* W3 = (const float*)d_in[6];
    const float* b3 = (const float*)d_in[7];
    float* out = (float*)d_out;
    const int* row = ei;            // edge_index[0]
    const int* col = ei + NEDGES;   // edge_index[1]

    char* w = (char*)d_ws;
    auto alloc = [&](size_t b) { void* p = (void*)w; w += (b + 255) & ~(size_t)255; return p; };
    int*   cnt  = (int*)alloc(NNODES * 4);
    int*   cur  = (int*)alloc(NNODES * 4);
    int*   rp   = (int*)alloc((NNODES + 1) * 4);
    float* dinv = (float*)alloc(NNODES * 4);
    int*   csr  = (int*)alloc((size_t)NEDGES * 4);
    float* h    = (float*)alloc((size_t)NNODES * HDIM * 4);
    float* a    = (float*)alloc((size_t)NNODES * HDIM * 4);
    float* h3   = h;   // reuse: mm2 output fully consumed by agg2 before mm3 writes

    hipMemsetAsync(cnt, 0, NNODES * 4, stream);
    hipMemsetAsync(cur, 0, NNODES * 4, stream);
    count_kernel<<<(NEDGES + 255) / 256, 256, 0, stream>>>(col, cnt, NEDGES);
    dinv_kernel<<<(NNODES + 255) / 256, 256, 0, stream>>>(cnt, dinv, NNODES);
    scan_kernel<<<1, 1024, 0, stream>>>(cnt, rp, NNODES, NEDGES);
    fill_kernel<<<(NEDGES + 255) / 256, 256, 0, stream>>>(row, col, rp, cur, csr, NEDGES);

    dim3 g1((NNODES + 63) / 64, HDIM / 64);
    mm_kernel<<<g1, 256, 0, stream>>>(x, W1, h, NNODES, FIN, HDIM);
    agg_kernel<<<(NNODES + 3) / 4, 256, 0, stream>>>((const float4*)h, (float4*)a,
                                                     dinv, rp, csr, b1, NNODES);
    mm_kernel<<<g1, 256, 0, stream>>>(a, W2, h, NNODES, HDIM, HDIM);
    agg_kernel<<<(NNODES + 3) / 4, 256, 0, stream>>>((const float4*)h, (float4*)a,
                                                     dinv, rp, csr, b2, NNODES);
    mm3_kernel<<<(NNODES + 3) / 4, 256, 0, stream>>>((const float4*)a, W3, h3, NNODES);
    final_kernel<<<(NNODES + 255) / 256, 256, 0, stream>>>(h3, dinv, rp, csr, b3, out, NNODES);
}

// Round 2
// 987.435 us; speedup vs baseline: 1.9095x; 1.9095x over previous
//
#include <hip/hip_runtime.h>
#include <math.h>

#define NNODES 50000
#define NEDGES 800000
#define FIN    1433
#define KP1    1440   // FIN padded to multiple of 32
#define HDIM   256
#define NCLS   7
#define MPAD   50048  // NNODES padded to multiple of 128

typedef __attribute__((ext_vector_type(8))) short short8;
typedef __attribute__((ext_vector_type(4))) float f32x4;

__device__ __forceinline__ unsigned short f2bf(float f) {
    unsigned u = __builtin_bit_cast(unsigned, f);
    u += 0x7fffu + ((u >> 16) & 1u);          // round-to-nearest-even
    return (unsigned short)(u >> 16);
}

__device__ __forceinline__ void gl2lds16(const void* g, void* l) {
    __builtin_amdgcn_global_load_lds(
        (const __attribute__((address_space(1))) unsigned int*)g,
        (__attribute__((address_space(3))) unsigned int*)l, 16, 0, 0);
}

// ---------------- CSR construction ----------------

__global__ void count_kernel(const int* __restrict__ col, int* __restrict__ cnt, int E) {
    int e = blockIdx.x * blockDim.x + threadIdx.x;
    if (e < E) atomicAdd(&cnt[col[e]], 1);
}

__global__ void dinv_kernel(const int* __restrict__ cnt, float* __restrict__ dinv, int n) {
    int i = blockIdx.x * blockDim.x + threadIdx.x;
    if (i < n) dinv[i] = rsqrtf((float)(cnt[i] + 1));   // +1 = self loop
}

__global__ __launch_bounds__(1024) void scan_kernel(const int* __restrict__ cnt,
                                                    int* __restrict__ rp, int n, int total) {
    __shared__ int sums[1024];
    int t = threadIdx.x;
    int chunk = (n + 1023) >> 10;
    int start = t * chunk;
    int end = start + chunk; if (end > n) end = n;
    int local = 0;
    for (int j = start; j < end; ++j) local += cnt[j];
    sums[t] = local;
    __syncthreads();
    for (int off = 1; off < 1024; off <<= 1) {
        int v = (t >= off) ? sums[t - off] : 0;
        __syncthreads();
        sums[t] += v;
        __syncthreads();
    }
    int run = (t == 0) ? 0 : sums[t - 1];
    for (int j = start; j < end; ++j) { rp[j] = run; run += cnt[j]; }
    if (t == 0) rp[n] = total;
}

__global__ void fill_kernel(const int* __restrict__ row, const int* __restrict__ col,
                            const int* __restrict__ rp, int* __restrict__ cur,
                            int* __restrict__ csr, int E) {
    int e = blockIdx.x * blockDim.x + threadIdx.x;
    if (e < E) {
        int c = col[e];
        int pos = rp[c] + atomicAdd(&cur[c], 1);
        csr[pos] = row[e];
    }
}

// ---------------- bf16 casts ----------------

// xb[MPAD][KP1] <- x[NNODES][FIN], zero-padded. one thread per 4 elems.
__global__ void cast_x_kernel(const float* __restrict__ x, unsigned short* __restrict__ xb) {
    int idx = blockIdx.x * blockDim.x + threadIdx.x;
    int r = idx / (KP1 / 4);
    if (r >= MPAD) return;
    int c4 = (idx % (KP1 / 4)) * 4;
    unsigned short v[4];
    #pragma unroll
    for (int u = 0; u < 4; ++u) {
        int c = c4 + u;
        float f = (r < NNODES && c < FIN) ? x[(size_t)r * FIN + c] : 0.f;
        v[u] = f2bf(f);
    }
    *(ushort4*)&xb[(size_t)r * KP1 + c4] = make_ushort4(v[0], v[1], v[2], v[3]);
}

// Wt[Nn][Kp] <- transpose of W[Kin][Nn], zero-padded along K.
__global__ void cast_wt_kernel(const float* __restrict__ W, unsigned short* __restrict__ Wt,
                               int Kin, int Kp, int Nn) {
    int idx = blockIdx.x * blockDim.x + threadIdx.x;
    if (idx >= Nn * Kp) return;
    int n = idx / Kp, k = idx % Kp;
    float f = (k < Kin) ? W[(size_t)k * Nn + n] : 0.f;
    Wt[idx] = f2bf(f);
}

// ab[MPAD][256] <- a[NNODES][256], zero-padded rows. one thread per 4 elems.
__global__ void cast_a_kernel(const float4* __restrict__ a, unsigned short* __restrict__ ab) {
    int idx = blockIdx.x * blockDim.x + threadIdx.x;
    if (idx >= MPAD * 64) return;
    int r = idx >> 6;
    float4 f = (r < NNODES) ? a[idx] : make_float4(0.f, 0.f, 0.f, 0.f);
    *(ushort4*)&ab[(size_t)idx * 4] = make_ushort4(f2bf(f.x), f2bf(f.y), f2bf(f.z), f2bf(f.w));
}

// ---------------- bf16 MFMA GEMM: C[M,Nn] f32 = A[MPAD,K] bf16 @ Bt[Nn,K]^T bf16 ----------
// 128x128 tile, BK=32, 256 threads = 4 waves, each wave 64x64.
// LDS chunk layout (16B chunks): chunk(m,kq) at m*4 + (kq ^ ((m>>1)&3))  -> staging via
// global_load_lds (wave base + lane*16) and ds_read_b128 both 2-way-per-bank (free).

__global__ __launch_bounds__(256) void gemm_bf16(const unsigned short* __restrict__ A,
                                                 const unsigned short* __restrict__ Bt,
                                                 float* __restrict__ C,
                                                 int M, int K, int Nn) {
    __shared__ __align__(16) unsigned short As[128 * 32];
    __shared__ __align__(16) unsigned short Bs[128 * 32];
    const int tid = threadIdx.x;
    const int wave = tid >> 6, lane = tid & 63;
    const int m0 = blockIdx.x * 128, n0 = blockIdx.y * 128;
    const int wm = (wave >> 1) * 64, wn = (wave & 1) * 64;

    // staging: chunk c handled by this thread: c = i*256 + wave*64 + lane, i in {0,1}
    const int c0 = wave * 64 + lane;
    const int c1 = 256 + wave * 64 + lane;
    int mA0 = c0 >> 2, kqA0 = (c0 & 3) ^ ((mA0 >> 1) & 3);
    int mA1 = c1 >> 2, kqA1 = (c1 & 3) ^ ((mA1 >> 1) & 3);
    const unsigned short* pA0 = A + (size_t)(m0 + mA0) * K + kqA0 * 8;
    const unsigned short* pA1 = A + (size_t)(m0 + mA1) * K + kqA1 * 8;
    const unsigned short* pB0 = Bt + (size_t)(n0 + mA0) * K + kqA0 * 8;
    const unsigned short* pB1 = Bt + (size_t)(n0 + mA1) * K + kqA1 * 8;
    unsigned short* ldsA0 = &As[(wave * 64) * 8];
    unsigned short* ldsA1 = &As[(256 + wave * 64) * 8];
    unsigned short* ldsB0 = &Bs[(wave * 64) * 8];
    unsigned short* ldsB1 = &Bs[(256 + wave * 64) * 8];

    // LDS fragment read offsets (constant over K loop)
    int aoff[4], boff[4];
    const int kq = lane >> 4;
    #pragma unroll
    for (int i = 0; i < 4; ++i) {
        int ml = wm + i * 16 + (lane & 15);
        aoff[i] = (ml * 4 + (kq ^ ((ml >> 1) & 3))) * 8;
        int nl = wn + i * 16 + (lane & 15);
        boff[i] = (nl * 4 + (kq ^ ((nl >> 1) & 3))) * 8;
    }

    f32x4 acc[4][4] = {};

    for (int k0 = 0; k0 < K; k0 += 32) {
        gl2lds16(pA0, ldsA0);
        gl2lds16(pA1, ldsA1);
        gl2lds16(pB0, ldsB0);
        gl2lds16(pB1, ldsB1);
        pA0 += 32; pA1 += 32; pB0 += 32; pB1 += 32;
        __syncthreads();
        short8 af[4], bfr[4];
        #pragma unroll
        for (int i = 0; i < 4; ++i) af[i]  = *(const short8*)&As[aoff[i]];
        #pragma unroll
        for (int j = 0; j < 4; ++j) bfr[j] = *(const short8*)&Bs[boff[j]];
        #pragma unroll
        for (int i = 0; i < 4; ++i)
            #pragma unroll
            for (int j = 0; j < 4; ++j)
                acc[i][j] = __builtin_amdgcn_mfma_f32_16x16x32_bf16(af[i], bfr[j], acc[i][j], 0, 0, 0);
        __syncthreads();
    }

    // C/D layout: col = lane&15, row = (lane>>4)*4 + reg
    #pragma unroll
    for (int i = 0; i < 4; ++i) {
        int gm_base = m0 + wm + i * 16 + (lane >> 4) * 4;
        #pragma unroll
        for (int r = 0; r < 4; ++r) {
            int gm = gm_base + r;
            if (gm < M) {
                #pragma unroll
                for (int j = 0; j < 4; ++j) {
                    int gn = n0 + wn + j * 16 + (lane & 15);
                    C[(size_t)gm * Nn + gn] = acc[i][j][r];
                }
            }
        }
    }
}

// ---------------- aggregation (F=256): one wave per node, float4 per lane ----------------

__global__ __launch_bounds__(256) void agg_kernel(const float4* __restrict__ h,
                                                  float4* __restrict__ out,
                                                  const float* __restrict__ dinv,
                                                  const int* __restrict__ rp,
                                                  const int* __restrict__ csr,
                                                  const float* __restrict__ bias,
                                                  int n) {
    int node = blockIdx.x * 4 + (threadIdx.x >> 6);
    int lane = threadIdx.x & 63;
    if (node >= n) return;
    float di = dinv[node];
    float4 acc = h[node * 64 + lane];
    float sw = di * di;
    acc.x *= sw; acc.y *= sw; acc.z *= sw; acc.w *= sw;
    int p0 = rp[node], p1 = rp[node + 1];
    for (int p = p0; p < p1; ++p) {
        int s = csr[p];
        float wgt = dinv[s] * di;
        float4 hv = h[s * 64 + lane];
        acc.x += wgt * hv.x; acc.y += wgt * hv.y;
        acc.z += wgt * hv.z; acc.w += wgt * hv.w;
    }
    float4 b = ((const float4*)bias)[lane];
    acc.x = fmaxf(acc.x + b.x, 0.f);
    acc.y = fmaxf(acc.y + b.y, 0.f);
    acc.z = fmaxf(acc.z + b.z, 0.f);
    acc.w = fmaxf(acc.w + b.w, 0.f);
    out[node * 64 + lane] = acc;
}

// ---------------- layer-3 matmul: h3[N,7] = a[N,256] @ W3[256,7] ----------------

__global__ __launch_bounds__(256) void mm3_kernel(const float4* __restrict__ a,
                                                  const float* __restrict__ W3,
                                                  float* __restrict__ h3, int n) {
    __shared__ float Ws[HDIM * NCLS];
    int tid = threadIdx.x;
    #pragma unroll
    for (int k = 0; k < 7; ++k) Ws[tid + k * 256] = W3[tid + k * 256];
    __syncthreads();
    int node = blockIdx.x * 4 + (tid >> 6);
    int lane = tid & 63;
    if (node < n) {
        float4 av = a[node * 64 + lane];
        float av4[4] = {av.x, av.y, av.z, av.w};
        const float* w0 = &Ws[(4 * lane) * NCLS];
        float p[NCLS] = {};
        #pragma unroll
        for (int j = 0; j < 4; ++j)
            #pragma unroll
            for (int c = 0; c < NCLS; ++c)
                p[c] += av4[j] * w0[j * NCLS + c];
        #pragma unroll
        for (int c = 0; c < NCLS; ++c) {
            float v = p[c];
            for (int off = 32; off > 0; off >>= 1) v += __shfl_down(v, off);
            if (lane == 0) h3[node * NCLS + c] = v;
        }
    }
}

// ---------------- layer-3 aggregation + bias + log_softmax ----------------

__global__ void final_kernel(const float* __restrict__ h3, const float* __restrict__ dinv,
                             const int* __restrict__ rp, const int* __restrict__ csr,
                             const float* __restrict__ b3, float* __restrict__ out, int n) {
    int i = blockIdx.x * blockDim.x + threadIdx.x;
    if (i >= n) return;
    float di = dinv[i];
    float sw = di * di;
    float acc[NCLS];
    #pragma unroll
    for (int c = 0; c < NCLS; ++c) acc[c] = sw * h3[i * NCLS + c];
    int p0 = rp[i], p1 = rp[i + 1];
    for (int p = p0; p < p1; ++p) {
        int s = csr[p];
        float wgt = dinv[s] * di;
        #pragma unroll
        for (int c = 0; c < NCLS; ++c) acc[c] += wgt * h3[s * NCLS + c];
    }
    float mx = -1e30f;
    #pragma unroll
    for (int c = 0; c < NCLS; ++c) { acc[c] += b3[c]; mx = fmaxf(mx, acc[c]); }
    float sum = 0.f;
    #pragma unroll
    for (int c = 0; c < NCLS; ++c) sum += expf(acc[c] - mx);
    float lse = mx + logf(sum);
    #pragma unroll
    for (int c = 0; c < NCLS; ++c) out[i * NCLS + c] = acc[c] - lse;
}

// ---------------- launch ----------------

extern "C" void kernel_launch(void* const* d_in, const int* in_sizes, int n_in,
                              void* d_out, int out_size, void* d_ws, size_t ws_size,
                              hipStream_t stream) {
    const float* x  = (const float*)d_in[0];
    const int*   ei = (const int*)d_in[1];
    const float* W1 = (const float*)d_in[2];
    const float* b1 = (const float*)d_in[3];
    const float* W2 = (const float*)d_in[4];
    const float* b2 = (const float*)d_in[5];
    const float* W3 = (const float*)d_in[6];
    const float* b3 = (const float*)d_in[7];
    float* out = (float*)d_out;
    const int* row = ei;
    const int* col = ei + NEDGES;

    char* w = (char*)d_ws;
    auto alloc = [&](size_t b) { void* p = (void*)w; w += (b + 255) & ~(size_t)255; return p; };
    int*   cnt  = (int*)alloc(NNODES * 4);
    int*   cur  = (int*)alloc(NNODES * 4);
    int*   rp   = (int*)alloc((NNODES + 1) * 4);
    float* dinv = (float*)alloc(NNODES * 4);
    int*   csr  = (int*)alloc((size_t)NEDGES * 4);
    float* h    = (float*)alloc((size_t)NNODES * HDIM * 4);
    float* a    = (float*)alloc((size_t)NNODES * HDIM * 4);
    unsigned short* xb  = (unsigned short*)alloc((size_t)MPAD * KP1 * 2);   // 144 MB
    unsigned short* w1t = (unsigned short*)alloc((size_t)HDIM * KP1 * 2);
    unsigned short* w2t = (unsigned short*)alloc((size_t)HDIM * HDIM * 2);
    unsigned short* ab  = xb;   // reuse: xb dead after gemm1
    float* h3 = h;              // reuse: mm2 output consumed by agg2 before mm3 writes

    hipMemsetAsync(cnt, 0, NNODES * 4, stream);
    hipMemsetAsync(cur, 0, NNODES * 4, stream);
    count_kernel<<<(NEDGES + 255) / 256, 256, 0, stream>>>(col, cnt, NEDGES);
    dinv_kernel<<<(NNODES + 255) / 256, 256, 0, stream>>>(cnt, dinv, NNODES);
    scan_kernel<<<1, 1024, 0, stream>>>(cnt, rp, NNODES, NEDGES);
    fill_kernel<<<(NEDGES + 255) / 256, 256, 0, stream>>>(row, col, rp, cur, csr, NEDGES);

    cast_x_kernel<<<(MPAD * (KP1 / 4) + 255) / 256, 256, 0, stream>>>(x, xb);
    cast_wt_kernel<<<(HDIM * KP1 + 255) / 256, 256, 0, stream>>>(W1, w1t, FIN, KP1, HDIM);
    cast_wt_kernel<<<(HDIM * HDIM + 255) / 256, 256, 0, stream>>>(W2, w2t, HDIM, HDIM, HDIM);

    dim3 g1(MPAD / 128, HDIM / 128);
    gemm_bf16<<<g1, 256, 0, stream>>>(xb, w1t, h, NNODES, KP1, HDIM);
    agg_kernel<<<(NNODES + 3) / 4, 256, 0, stream>>>((const float4*)h, (float4*)a,
                                                     dinv, rp, csr, b1, NNODES);
    cast_a_kernel<<<(MPAD * 64 + 255) / 256, 256, 0, stream>>>((const float4*)a, ab);
    gemm_bf16<<<g1, 256, 0, stream>>>(ab, w2t, h, NNODES, HDIM, HDIM);
    agg_kernel<<<(NNODES + 3) / 4, 256, 0, stream>>>((const float4*)h, (float4*)a,
                                                     dinv, rp, csr, b2, NNODES);
    mm3_kernel<<<(NNODES + 3) / 4, 256, 0, stream>>>((const float4*)a, W3, h3, NNODES);
    final_kernel<<<(NNODES + 255) / 256, 256, 0, stream>>>(h3, dinv, rp, csr, b3, out, NNODES);
}

// Round 3
// 913.565 us; speedup vs baseline: 2.0639x; 1.0809x over previous
//
#include <hip/hip_runtime.h>
#include <math.h>

#define NNODES 50000
#define NEDGES 800000
#define FIN    1433
#define KP1    1440   // FIN padded to multiple of 32
#define HDIM   256
#define NCLS   7
#define MPAD   50048  // NNODES padded to multiple of 128

typedef __attribute__((ext_vector_type(8))) short short8;
typedef __attribute__((ext_vector_type(4))) float f32x4;

__device__ __forceinline__ unsigned short f2bf(float f) {
    unsigned u = __builtin_bit_cast(unsigned, f);
    u += 0x7fffu + ((u >> 16) & 1u);          // round-to-nearest-even
    return (unsigned short)(u >> 16);
}

__device__ __forceinline__ float bf2f(unsigned short u) {
    unsigned v = ((unsigned)u) << 16;
    return __builtin_bit_cast(float, v);
}

__device__ __forceinline__ void gl2lds16(const void* g, void* l) {
    __builtin_amdgcn_global_load_lds(
        (const __attribute__((address_space(1))) unsigned int*)g,
        (__attribute__((address_space(3))) unsigned int*)l, 16, 0, 0);
}

// ---------------- CSR construction ----------------

__global__ void count_kernel(const int* __restrict__ col, int* __restrict__ cnt, int E) {
    int e = blockIdx.x * blockDim.x + threadIdx.x;
    if (e < E) atomicAdd(&cnt[col[e]], 1);
}

__global__ void dinv_kernel(const int* __restrict__ cnt, float* __restrict__ dinv, int n) {
    int i = blockIdx.x * blockDim.x + threadIdx.x;
    if (i < n) dinv[i] = rsqrtf((float)(cnt[i] + 1));   // +1 = self loop
}

__global__ __launch_bounds__(1024) void scan_kernel(const int* __restrict__ cnt,
                                                    int* __restrict__ rp, int n, int total) {
    __shared__ int sums[1024];
    int t = threadIdx.x;
    int chunk = (n + 1023) >> 10;
    int start = t * chunk;
    int end = start + chunk; if (end > n) end = n;
    int local = 0;
    for (int j = start; j < end; ++j) local += cnt[j];
    sums[t] = local;
    __syncthreads();
    for (int off = 1; off < 1024; off <<= 1) {
        int v = (t >= off) ? sums[t - off] : 0;
        __syncthreads();
        sums[t] += v;
        __syncthreads();
    }
    int run = (t == 0) ? 0 : sums[t - 1];
    for (int j = start; j < end; ++j) { rp[j] = run; run += cnt[j]; }
    if (t == 0) rp[n] = total;
}

__global__ void fill_kernel(const int* __restrict__ row, const int* __restrict__ col,
                            const int* __restrict__ rp, int* __restrict__ cur,
                            int* __restrict__ csr, int E) {
    int e = blockIdx.x * blockDim.x + threadIdx.x;
    if (e < E) {
        int c = col[e];
        int pos = rp[c] + atomicAdd(&cur[c], 1);
        csr[pos] = row[e];
    }
}

// ---------------- bf16 casts ----------------

// xb[MPAD][KP1] <- x[NNODES][FIN], zero-padded.
__global__ void cast_x_kernel(const float* __restrict__ x, unsigned short* __restrict__ xb) {
    int idx = blockIdx.x * blockDim.x + threadIdx.x;
    int r = idx / (KP1 / 4);
    if (r >= MPAD) return;
    int c4 = (idx % (KP1 / 4)) * 4;
    unsigned short v[4];
    #pragma unroll
    for (int u = 0; u < 4; ++u) {
        int c = c4 + u;
        float f = (r < NNODES && c < FIN) ? x[(size_t)r * FIN + c] : 0.f;
        v[u] = f2bf(f);
    }
    *(ushort4*)&xb[(size_t)r * KP1 + c4] = make_ushort4(v[0], v[1], v[2], v[3]);
}

// Wt[Nn][Kp] <- transpose of W[Kin][Nn], zero-padded along K.
__global__ void cast_wt_kernel(const float* __restrict__ W, unsigned short* __restrict__ Wt,
                               int Kin, int Kp, int Nn) {
    int idx = blockIdx.x * blockDim.x + threadIdx.x;
    if (idx >= Nn * Kp) return;
    int n = idx / Kp, k = idx % Kp;
    float f = (k < Kin) ? W[(size_t)k * Nn + n] : 0.f;
    Wt[idx] = f2bf(f);
}

// zero the pad rows of a bf16 [MPAD][256] buffer (rows NNODES..MPAD)
__global__ void zero_pad_kernel(unsigned short* __restrict__ b) {
    int idx = blockIdx.x * blockDim.x + threadIdx.x;
    int total = (MPAD - NNODES) * HDIM;
    if (idx < total) b[(size_t)NNODES * HDIM + idx] = 0;
}

// ---------------- bf16 MFMA GEMM: C[M,Nn] bf16 = A[MPAD,K] bf16 @ Bt[Nn,K]^T bf16 --------
// 128x128 tile, BK=32, 256 threads = 4 waves, each wave 64x64.
// LDS chunk layout (16B chunks): chunk(m,kq) at m*4 + (kq ^ ((m>>1)&3)).

__global__ __launch_bounds__(256) void gemm_bf16(const unsigned short* __restrict__ A,
                                                 const unsigned short* __restrict__ Bt,
                                                 unsigned short* __restrict__ C,
                                                 int M, int K, int Nn) {
    __shared__ __align__(16) unsigned short As[128 * 32];
    __shared__ __align__(16) unsigned short Bs[128 * 32];
    const int tid = threadIdx.x;
    const int wave = tid >> 6, lane = tid & 63;
    const int m0 = blockIdx.x * 128, n0 = blockIdx.y * 128;
    const int wm = (wave >> 1) * 64, wn = (wave & 1) * 64;

    const int c0 = wave * 64 + lane;
    const int c1 = 256 + wave * 64 + lane;
    int mA0 = c0 >> 2, kqA0 = (c0 & 3) ^ ((mA0 >> 1) & 3);
    int mA1 = c1 >> 2, kqA1 = (c1 & 3) ^ ((mA1 >> 1) & 3);
    const unsigned short* pA0 = A + (size_t)(m0 + mA0) * K + kqA0 * 8;
    const unsigned short* pA1 = A + (size_t)(m0 + mA1) * K + kqA1 * 8;
    const unsigned short* pB0 = Bt + (size_t)(n0 + mA0) * K + kqA0 * 8;
    const unsigned short* pB1 = Bt + (size_t)(n0 + mA1) * K + kqA1 * 8;
    unsigned short* ldsA0 = &As[(wave * 64) * 8];
    unsigned short* ldsA1 = &As[(256 + wave * 64) * 8];
    unsigned short* ldsB0 = &Bs[(wave * 64) * 8];
    unsigned short* ldsB1 = &Bs[(256 + wave * 64) * 8];

    int aoff[4], boff[4];
    const int kq = lane >> 4;
    #pragma unroll
    for (int i = 0; i < 4; ++i) {
        int ml = wm + i * 16 + (lane & 15);
        aoff[i] = (ml * 4 + (kq ^ ((ml >> 1) & 3))) * 8;
        int nl = wn + i * 16 + (lane & 15);
        boff[i] = (nl * 4 + (kq ^ ((nl >> 1) & 3))) * 8;
    }

    f32x4 acc[4][4] = {};

    for (int k0 = 0; k0 < K; k0 += 32) {
        gl2lds16(pA0, ldsA0);
        gl2lds16(pA1, ldsA1);
        gl2lds16(pB0, ldsB0);
        gl2lds16(pB1, ldsB1);
        pA0 += 32; pA1 += 32; pB0 += 32; pB1 += 32;
        __syncthreads();
        short8 af[4], bfr[4];
        #pragma unroll
        for (int i = 0; i < 4; ++i) af[i]  = *(const short8*)&As[aoff[i]];
        #pragma unroll
        for (int j = 0; j < 4; ++j) bfr[j] = *(const short8*)&Bs[boff[j]];
        #pragma unroll
        for (int i = 0; i < 4; ++i)
            #pragma unroll
            for (int j = 0; j < 4; ++j)
                acc[i][j] = __builtin_amdgcn_mfma_f32_16x16x32_bf16(af[i], bfr[j], acc[i][j], 0, 0, 0);
        __syncthreads();
    }

    // C/D layout: col = lane&15, row = (lane>>4)*4 + reg
    #pragma unroll
    for (int i = 0; i < 4; ++i) {
        int gm_base = m0 + wm + i * 16 + (lane >> 4) * 4;
        #pragma unroll
        for (int r = 0; r < 4; ++r) {
            int gm = gm_base + r;
            if (gm < M) {
                #pragma unroll
                for (int j = 0; j < 4; ++j) {
                    int gn = n0 + wn + j * 16 + (lane & 15);
                    C[(size_t)gm * Nn + gn] = f2bf(acc[i][j][r]);
                }
            }
        }
    }
}

// ---------------- aggregation (F=256, bf16 in/out): one wave per node ----------------

__global__ __launch_bounds__(256) void agg_kernel(const ushort4* __restrict__ h,
                                                  ushort4* __restrict__ out,
                                                  const float* __restrict__ dinv,
                                                  const int* __restrict__ rp,
                                                  const int* __restrict__ csr,
                                                  const float* __restrict__ bias,
                                                  int n) {
    int node = blockIdx.x * 4 + (threadIdx.x >> 6);
    int lane = threadIdx.x & 63;
    if (node >= n) return;
    float di = dinv[node];
    float sw = di * di;
    ushort4 hv = h[node * 64 + lane];
    float ax = sw * bf2f(hv.x), ay = sw * bf2f(hv.y);
    float az = sw * bf2f(hv.z), aw = sw * bf2f(hv.w);
    int p0 = rp[node], p1 = rp[node + 1];
    for (int p = p0; p < p1; ++p) {
        int s = csr[p];
        float wgt = dinv[s] * di;
        ushort4 t = h[s * 64 + lane];
        ax += wgt * bf2f(t.x); ay += wgt * bf2f(t.y);
        az += wgt * bf2f(t.z); aw += wgt * bf2f(t.w);
    }
    float4 b = ((const float4*)bias)[lane];
    ax = fmaxf(ax + b.x, 0.f); ay = fmaxf(ay + b.y, 0.f);
    az = fmaxf(az + b.z, 0.f); aw = fmaxf(aw + b.w, 0.f);
    out[node * 64 + lane] = make_ushort4(f2bf(ax), f2bf(ay), f2bf(az), f2bf(aw));
}

// ---------------- layer-3 matmul: h3[N,7] = a[N,256] bf16 @ W3[256,7] f32 ----------------

__global__ __launch_bounds__(256) void mm3_kernel(const ushort4* __restrict__ a,
                                                  const float* __restrict__ W3,
                                                  float* __restrict__ h3, int n) {
    __shared__ float Ws[HDIM * NCLS];
    int tid = threadIdx.x;
    #pragma unroll
    for (int k = 0; k < 7; ++k) Ws[tid + k * 256] = W3[tid + k * 256];
    __syncthreads();
    int node = blockIdx.x * 4 + (tid >> 6);
    int lane = tid & 63;
    if (node < n) {
        ushort4 av = a[node * 64 + lane];
        float av4[4] = {bf2f(av.x), bf2f(av.y), bf2f(av.z), bf2f(av.w)};
        const float* w0 = &Ws[(4 * lane) * NCLS];
        float p[NCLS] = {};
        #pragma unroll
        for (int j = 0; j < 4; ++j)
            #pragma unroll
            for (int c = 0; c < NCLS; ++c)
                p[c] += av4[j] * w0[j * NCLS + c];
        #pragma unroll
        for (int c = 0; c < NCLS; ++c) {
            float v = p[c];
            for (int off = 32; off > 0; off >>= 1) v += __shfl_down(v, off);
            if (lane == 0) h3[node * NCLS + c] = v;
        }
    }
}

// ---------------- layer-3 aggregation + bias + log_softmax ----------------

__global__ void final_kernel(const float* __restrict__ h3, const float* __restrict__ dinv,
                             const int* __restrict__ rp, const int* __restrict__ csr,
                             const float* __restrict__ b3, float* __restrict__ out, int n) {
    int i = blockIdx.x * blockDim.x + threadIdx.x;
    if (i >= n) return;
    float di = dinv[i];
    float sw = di * di;
    float acc[NCLS];
    #pragma unroll
    for (int c = 0; c < NCLS; ++c) acc[c] = sw * h3[i * NCLS + c];
    int p0 = rp[i], p1 = rp[i + 1];
    for (int p = p0; p < p1; ++p) {
        int s = csr[p];
        float wgt = dinv[s] * di;
        #pragma unroll
        for (int c = 0; c < NCLS; ++c) acc[c] += wgt * h3[s * NCLS + c];
    }
    float mx = -1e30f;
    #pragma unroll
    for (int c = 0; c < NCLS; ++c) { acc[c] += b3[c]; mx = fmaxf(mx, acc[c]); }
    float sum = 0.f;
    #pragma unroll
    for (int c = 0; c < NCLS; ++c) sum += expf(acc[c] - mx);
    float lse = mx + logf(sum);
    #pragma unroll
    for (int c = 0; c < NCLS; ++c) out[i * NCLS + c] = acc[c] - lse;
}

// ---------------- launch ----------------

extern "C" void kernel_launch(void* const* d_in, const int* in_sizes, int n_in,
                              void* d_out, int out_size, void* d_ws, size_t ws_size,
                              hipStream_t stream) {
    const float* x  = (const float*)d_in[0];
    const int*   ei = (const int*)d_in[1];
    const float* W1 = (const float*)d_in[2];
    const float* b1 = (const float*)d_in[3];
    const float* W2 = (const float*)d_in[4];
    const float* b2 = (const float*)d_in[5];
    const float* W3 = (const float*)d_in[6];
    const float* b3 = (const float*)d_in[7];
    float* out = (float*)d_out;
    const int* row = ei;
    const int* col = ei + NEDGES;

    char* w = (char*)d_ws;
    auto alloc = [&](size_t b) { void* p = (void*)w; w += (b + 255) & ~(size_t)255; return p; };
    int*   cnt  = (int*)alloc(NNODES * 4);
    int*   cur  = (int*)alloc(NNODES * 4);
    int*   rp   = (int*)alloc((NNODES + 1) * 4);
    float* dinv = (float*)alloc(NNODES * 4);
    int*   csr  = (int*)alloc((size_t)NEDGES * 4);
    unsigned short* xb   = (unsigned short*)alloc((size_t)MPAD * KP1 * 2);   // 144 MB
    unsigned short* w1t  = (unsigned short*)alloc((size_t)HDIM * KP1 * 2);
    unsigned short* w2t  = (unsigned short*)alloc((size_t)HDIM * HDIM * 2);
    unsigned short* h_bf = (unsigned short*)alloc((size_t)MPAD * HDIM * 2);  // 25.6 MB
    unsigned short* a_bf = (unsigned short*)alloc((size_t)MPAD * HDIM * 2);  // 25.6 MB
    float* h3 = (float*)alloc((size_t)NNODES * NCLS * 4);

    hipMemsetAsync(cnt, 0, NNODES * 4, stream);
    hipMemsetAsync(cur, 0, NNODES * 4, stream);
    zero_pad_kernel<<<((MPAD - NNODES) * HDIM + 255) / 256, 256, 0, stream>>>(a_bf);
    count_kernel<<<(NEDGES + 255) / 256, 256, 0, stream>>>(col, cnt, NEDGES);
    dinv_kernel<<<(NNODES + 255) / 256, 256, 0, stream>>>(cnt, dinv, NNODES);
    scan_kernel<<<1, 1024, 0, stream>>>(cnt, rp, NNODES, NEDGES);
    fill_kernel<<<(NEDGES + 255) / 256, 256, 0, stream>>>(row, col, rp, cur, csr, NEDGES);

    cast_x_kernel<<<(MPAD * (KP1 / 4) + 255) / 256, 256, 0, stream>>>(x, xb);
    cast_wt_kernel<<<(HDIM * KP1 + 255) / 256, 256, 0, stream>>>(W1, w1t, FIN, KP1, HDIM);
    cast_wt_kernel<<<(HDIM * HDIM + 255) / 256, 256, 0, stream>>>(W2, w2t, HDIM, HDIM, HDIM);

    dim3 g1(MPAD / 128, HDIM / 128);
    gemm_bf16<<<g1, 256, 0, stream>>>(xb, w1t, h_bf, NNODES, KP1, HDIM);
    agg_kernel<<<(NNODES + 3) / 4, 256, 0, stream>>>((const ushort4*)h_bf, (ushort4*)a_bf,
                                                     dinv, rp, csr, b1, NNODES);
    gemm_bf16<<<g1, 256, 0, stream>>>(a_bf, w2t, h_bf, NNODES, HDIM, HDIM);
    agg_kernel<<<(NNODES + 3) / 4, 256, 0, stream>>>((const ushort4*)h_bf, (ushort4*)a_bf,
                                                     dinv, rp, csr, b2, NNODES);
    mm3_kernel<<<(NNODES + 3) / 4, 256, 0, stream>>>((const ushort4*)a_bf, W3, h3, NNODES);
    final_kernel<<<(NNODES + 255) / 256, 256, 0, stream>>>(h3, dinv, rp, csr, b3, out, NNODES);
}